// Round 9
// baseline (322.068 us; speedup 1.0000x reference)
//
#include <hip/hip_runtime.h>
#include <hip/hip_bf16.h>

typedef float f32x4 __attribute__((ext_vector_type(4)));
typedef short bf16x8 __attribute__((ext_vector_type(8)));

#define MFMA16 __builtin_amdgcn_mfma_f32_16x16x32_bf16

static constexpr int KDIM = 1700;
static constexpr int NKT  = 54;         // k-tiles of 32 (tile 53 ragged: 4 valid)
static constexpr float BETA = 0.9f;
static constexpr float THRESH = 1.0f;

// fp32 -> bf16 hi + bf16 lo (residual), via HW cvt
__device__ __forceinline__ void split_bf(float f, short& hi, short& lo) {
    __hip_bfloat16 h = __float2bfloat16(f);
    float r = f - __bfloat162float(h);          // exact in fp32
    __hip_bfloat16 l = __float2bfloat16(r);
    hi = (short)__builtin_bit_cast(unsigned short, h);
    lo = (short)__builtin_bit_cast(unsigned short, l);
}

__device__ __forceinline__ void split8(f32x4 a, f32x4 b, bf16x8& hi, bf16x8& lo) {
    #pragma unroll
    for (int i = 0; i < 4; ++i) { short h, l; split_bf(a[i], h, l); hi[i] = h; lo[i] = l; }
    #pragma unroll
    for (int i = 0; i < 4; ++i) { short h, l; split_bf(b[i], h, l); hi[4 + i] = h; lo[4 + i] = l; }
}

// W1 [64][1700] f32 -> two bf16 planes in MFMA-B-fragment order:
// WT[((kt*4 + nt)*64 + lane)*8 + i] = W1[nt*16 + (lane&15)][kt*32 + (lane>>4)*8 + i]
__global__ void w1_relayout(const float* __restrict__ W1,
                            short* __restrict__ WTh, short* __restrict__ WTl) {
    const int g    = blockIdx.x * 256 + threadIdx.x;   // 0 .. 54*256-1
    const int kt   = g >> 8;
    const int nt   = (g >> 6) & 3;
    const int lane = g & 63;
    const int n    = nt * 16 + (lane & 15);
    const int kb   = kt * 32 + (lane >> 4) * 8;
    bf16x8 vh, vl;
    #pragma unroll
    for (int i = 0; i < 8; ++i) {
        const int k = kb + i;
        const float v = (k < KDIM) ? W1[n * KDIM + k] : 0.f;
        short h, l; split_bf(v, h, l);
        vh[i] = h; vl[i] = l;
    }
    *(bf16x8*)(WTh + (size_t)g * 8) = vh;
    *(bf16x8*)(WTl + (size_t)g * 8) = vl;
}

// ============================ ABLATION PROBES ================================
// All three share r3-gemm1's exact structure (K-split-4, 1-deep x prefetch,
// per-rep LDS reduce + global write). Results go to scratch; unused.

// V0: full loop (baseline timing reference)
__global__ __launch_bounds__(256, 2) void probe_base(
    const float* __restrict__ x,
    const short* __restrict__ WTh, const short* __restrict__ WTl,
    const float* __restrict__ b1, float* __restrict__ pout, int REP)
{
    __shared__ float red[4][32][68];
    const int tid = threadIdx.x;
    const int wid = tid >> 6;
    const int lane = tid & 63;
    const int l15 = lane & 15;
    const int g4  = lane >> 4;
    const int kg  = g4 * 8;
    const int rowBase = blockIdx.x * 32;
    const int t0  = wid * 13 + (wid < 2 ? wid : 2);
    const int t1  = t0 + 14 - (wid >> 1);
    const int t1e = (wid == 3) ? 53 : t1;
    const float* xr0 = x + (size_t)(rowBase + l15) * KDIM + kg;
    const float* xr1 = xr0 + (size_t)16 * KDIM;

    for (int rep = 0; rep < REP; ++rep) {
        f32x4 acc[2][4] = {};
        f32x4 p00 = *(const f32x4*)(xr0 + t0 * 32);
        f32x4 p01 = *(const f32x4*)(xr0 + t0 * 32 + 4);
        f32x4 p10 = *(const f32x4*)(xr1 + t0 * 32);
        f32x4 p11 = *(const f32x4*)(xr1 + t0 * 32 + 4);
        for (int t = t0; t < t1e; ++t) {
            f32x4 a00 = p00, a01 = p01, a10 = p10, a11 = p11;
            if (t + 1 < t1e) {
                p00 = *(const f32x4*)(xr0 + (t + 1) * 32);
                p01 = *(const f32x4*)(xr0 + (t + 1) * 32 + 4);
                p10 = *(const f32x4*)(xr1 + (t + 1) * 32);
                p11 = *(const f32x4*)(xr1 + (t + 1) * 32 + 4);
            }
            const short* wb = WTh + (size_t)t * 2048 + lane * 8;
            const short* wl = WTl + (size_t)t * 2048 + lane * 8;
            bf16x8 bh[4], bl[4];
            #pragma unroll
            for (int nt = 0; nt < 4; ++nt) {
                bh[nt] = *(const bf16x8*)(wb + nt * 512);
                bl[nt] = *(const bf16x8*)(wl + nt * 512);
            }
            bf16x8 ah0, al0, ah1, al1;
            split8(a00, a01, ah0, al0);
            split8(a10, a11, ah1, al1);
            #pragma unroll
            for (int nt = 0; nt < 4; ++nt) {
                acc[0][nt] = MFMA16(ah0, bh[nt], acc[0][nt], 0, 0, 0);
                acc[0][nt] = MFMA16(al0, bh[nt], acc[0][nt], 0, 0, 0);
                acc[0][nt] = MFMA16(ah0, bl[nt], acc[0][nt], 0, 0, 0);
                acc[1][nt] = MFMA16(ah1, bh[nt], acc[1][nt], 0, 0, 0);
                acc[1][nt] = MFMA16(al1, bh[nt], acc[1][nt], 0, 0, 0);
                acc[1][nt] = MFMA16(ah1, bl[nt], acc[1][nt], 0, 0, 0);
            }
        }
        #pragma unroll
        for (int mt = 0; mt < 2; ++mt)
            #pragma unroll
            for (int nt = 0; nt < 4; ++nt)
                #pragma unroll
                for (int j = 0; j < 4; ++j)
                    red[wid][mt * 16 + g4 * 4 + j][nt * 16 + l15] = acc[mt][nt][j];
        __syncthreads();
        {
            const int rr  = tid >> 3;
            const int seg = tid & 7;
            f32x4 s0 = *(const f32x4*)(b1 + seg * 8);
            f32x4 s1 = *(const f32x4*)(b1 + seg * 8 + 4);
            #pragma unroll
            for (int p = 0; p < 4; ++p) {
                s0 += *(const f32x4*)&red[p][rr][seg * 8];
                s1 += *(const f32x4*)&red[p][rr][seg * 8 + 4];
            }
            float* cp = pout + (size_t)(rowBase + rr) * 64 + seg * 8;
            *(f32x4*)cp = s0;
            *(f32x4*)(cp + 4) = s1;
        }
        __syncthreads();
    }
}

// V1: NO W loads in the loop (W fragments preloaded once into registers)
__global__ __launch_bounds__(256, 2) void probe_noW(
    const float* __restrict__ x,
    const short* __restrict__ WTh, const short* __restrict__ WTl,
    const float* __restrict__ b1, float* __restrict__ pout, int REP)
{
    __shared__ float red[4][32][68];
    const int tid = threadIdx.x;
    const int wid = tid >> 6;
    const int lane = tid & 63;
    const int l15 = lane & 15;
    const int g4  = lane >> 4;
    const int kg  = g4 * 8;
    const int rowBase = blockIdx.x * 32;
    const int t0  = wid * 13 + (wid < 2 ? wid : 2);
    const int t1  = t0 + 14 - (wid >> 1);
    const int t1e = (wid == 3) ? 53 : t1;
    const float* xr0 = x + (size_t)(rowBase + l15) * KDIM + kg;
    const float* xr1 = xr0 + (size_t)16 * KDIM;

    // preload one tile's W fragments; reused for every t (timing probe only)
    bf16x8 bhC[4], blC[4];
    #pragma unroll
    for (int nt = 0; nt < 4; ++nt) {
        bhC[nt] = *(const bf16x8*)(WTh + (size_t)t0 * 2048 + nt * 512 + lane * 8);
        blC[nt] = *(const bf16x8*)(WTl + (size_t)t0 * 2048 + nt * 512 + lane * 8);
    }

    for (int rep = 0; rep < REP; ++rep) {
        f32x4 acc[2][4] = {};
        f32x4 p00 = *(const f32x4*)(xr0 + t0 * 32);
        f32x4 p01 = *(const f32x4*)(xr0 + t0 * 32 + 4);
        f32x4 p10 = *(const f32x4*)(xr1 + t0 * 32);
        f32x4 p11 = *(const f32x4*)(xr1 + t0 * 32 + 4);
        for (int t = t0; t < t1e; ++t) {
            f32x4 a00 = p00, a01 = p01, a10 = p10, a11 = p11;
            if (t + 1 < t1e) {
                p00 = *(const f32x4*)(xr0 + (t + 1) * 32);
                p01 = *(const f32x4*)(xr0 + (t + 1) * 32 + 4);
                p10 = *(const f32x4*)(xr1 + (t + 1) * 32);
                p11 = *(const f32x4*)(xr1 + (t + 1) * 32 + 4);
            }
            bf16x8 ah0, al0, ah1, al1;
            split8(a00, a01, ah0, al0);
            split8(a10, a11, ah1, al1);
            #pragma unroll
            for (int nt = 0; nt < 4; ++nt) {
                acc[0][nt] = MFMA16(ah0, bhC[nt], acc[0][nt], 0, 0, 0);
                acc[0][nt] = MFMA16(al0, bhC[nt], acc[0][nt], 0, 0, 0);
                acc[0][nt] = MFMA16(ah0, blC[nt], acc[0][nt], 0, 0, 0);
                acc[1][nt] = MFMA16(ah1, bhC[nt], acc[1][nt], 0, 0, 0);
                acc[1][nt] = MFMA16(al1, bhC[nt], acc[1][nt], 0, 0, 0);
                acc[1][nt] = MFMA16(ah1, blC[nt], acc[1][nt], 0, 0, 0);
            }
        }
        #pragma unroll
        for (int mt = 0; mt < 2; ++mt)
            #pragma unroll
            for (int nt = 0; nt < 4; ++nt)
                #pragma unroll
                for (int j = 0; j < 4; ++j)
                    red[wid][mt * 16 + g4 * 4 + j][nt * 16 + l15] = acc[mt][nt][j];
        __syncthreads();
        {
            const int rr  = tid >> 3;
            const int seg = tid & 7;
            f32x4 s0 = *(const f32x4*)(b1 + seg * 8);
            f32x4 s1 = *(const f32x4*)(b1 + seg * 8 + 4);
            #pragma unroll
            for (int p = 0; p < 4; ++p) {
                s0 += *(const f32x4*)&red[p][rr][seg * 8];
                s1 += *(const f32x4*)&red[p][rr][seg * 8 + 4];
            }
            float* cp = pout + (size_t)(rowBase + rr) * 64 + seg * 8;
            *(f32x4*)cp = s0;
            *(f32x4*)(cp + 4) = s1;
        }
        __syncthreads();
    }
}

// V2: NO x loads in the loop (x regs preloaded once; asm-keep stops hoisting
// of split8 — rule #17). W loads kept exactly as baseline.
__global__ __launch_bounds__(256, 2) void probe_noX(
    const float* __restrict__ x,
    const short* __restrict__ WTh, const short* __restrict__ WTl,
    const float* __restrict__ b1, float* __restrict__ pout, int REP)
{
    __shared__ float red[4][32][68];
    const int tid = threadIdx.x;
    const int wid = tid >> 6;
    const int lane = tid & 63;
    const int l15 = lane & 15;
    const int g4  = lane >> 4;
    const int kg  = g4 * 8;
    const int rowBase = blockIdx.x * 32;
    const int t0  = wid * 13 + (wid < 2 ? wid : 2);
    const int t1  = t0 + 14 - (wid >> 1);
    const int t1e = (wid == 3) ? 53 : t1;
    const float* xr0 = x + (size_t)(rowBase + l15) * KDIM + kg;
    const float* xr1 = xr0 + (size_t)16 * KDIM;

    f32x4 a00 = *(const f32x4*)(xr0 + t0 * 32);
    f32x4 a01 = *(const f32x4*)(xr0 + t0 * 32 + 4);
    f32x4 a10 = *(const f32x4*)(xr1 + t0 * 32);
    f32x4 a11 = *(const f32x4*)(xr1 + t0 * 32 + 4);

    for (int rep = 0; rep < REP; ++rep) {
        f32x4 acc[2][4] = {};
        for (int t = t0; t < t1e; ++t) {
            asm volatile("" : "+v"(a00), "+v"(a01), "+v"(a10), "+v"(a11));
            const short* wb = WTh + (size_t)t * 2048 + lane * 8;
            const short* wl = WTl + (size_t)t * 2048 + lane * 8;
            bf16x8 bh[4], bl[4];
            #pragma unroll
            for (int nt = 0; nt < 4; ++nt) {
                bh[nt] = *(const bf16x8*)(wb + nt * 512);
                bl[nt] = *(const bf16x8*)(wl + nt * 512);
            }
            bf16x8 ah0, al0, ah1, al1;
            split8(a00, a01, ah0, al0);
            split8(a10, a11, ah1, al1);
            #pragma unroll
            for (int nt = 0; nt < 4; ++nt) {
                acc[0][nt] = MFMA16(ah0, bh[nt], acc[0][nt], 0, 0, 0);
                acc[0][nt] = MFMA16(al0, bh[nt], acc[0][nt], 0, 0, 0);
                acc[0][nt] = MFMA16(ah0, bl[nt], acc[0][nt], 0, 0, 0);
                acc[1][nt] = MFMA16(ah1, bh[nt], acc[1][nt], 0, 0, 0);
                acc[1][nt] = MFMA16(al1, bh[nt], acc[1][nt], 0, 0, 0);
                acc[1][nt] = MFMA16(ah1, bl[nt], acc[1][nt], 0, 0, 0);
            }
        }
        #pragma unroll
        for (int mt = 0; mt < 2; ++mt)
            #pragma unroll
            for (int nt = 0; nt < 4; ++nt)
                #pragma unroll
                for (int j = 0; j < 4; ++j)
                    red[wid][mt * 16 + g4 * 4 + j][nt * 16 + l15] = acc[mt][nt][j];
        __syncthreads();
        {
            const int rr  = tid >> 3;
            const int seg = tid & 7;
            f32x4 s0 = *(const f32x4*)(b1 + seg * 8);
            f32x4 s1 = *(const f32x4*)(b1 + seg * 8 + 4);
            #pragma unroll
            for (int p = 0; p < 4; ++p) {
                s0 += *(const f32x4*)&red[p][rr][seg * 8];
                s1 += *(const f32x4*)&red[p][rr][seg * 8 + 4];
            }
            float* cp = pout + (size_t)(rowBase + rr) * 64 + seg * 8;
            *(f32x4*)cp = s0;
            *(f32x4*)(cp + 4) = s1;
        }
        __syncthreads();
    }
}

// ============== real fused kernel (r8, unchanged — produces out) =============
__global__ __launch_bounds__(256, 2) void snn_fused(
    const float* __restrict__ x,
    const short* __restrict__ WTh, const short* __restrict__ WTl,
    const float* __restrict__ b1, const float* __restrict__ W2,
    const float* __restrict__ b2, const float* __restrict__ W3,
    const float* __restrict__ b3, const int* __restrict__ nsp,
    float* __restrict__ out)
{
    __shared__ float red[4][32][68];
    const int tid = threadIdx.x;
    const int wid = tid >> 6;
    const int lane = tid & 63;
    const int l15 = lane & 15;
    const int g4  = lane >> 4;
    const int kg  = g4 * 8;
    const int rowBase = blockIdx.x * 32;

    {
        const int t0  = wid * 13 + (wid < 2 ? wid : 2);
        const int t1  = t0 + 14 - (wid >> 1);
        const int t1e = (wid == 3) ? 53 : t1;
        const float* xr0 = x + (size_t)(rowBase + l15) * KDIM + kg;
        const float* xr1 = xr0 + (size_t)16 * KDIM;

        f32x4 acc[2][4] = {};
        f32x4 p00 = *(const f32x4*)(xr0 + t0 * 32);
        f32x4 p01 = *(const f32x4*)(xr0 + t0 * 32 + 4);
        f32x4 p10 = *(const f32x4*)(xr1 + t0 * 32);
        f32x4 p11 = *(const f32x4*)(xr1 + t0 * 32 + 4);

        for (int t = t0; t < t1e; ++t) {
            f32x4 a00 = p00, a01 = p01, a10 = p10, a11 = p11;
            if (t + 1 < t1e) {
                p00 = *(const f32x4*)(xr0 + (t + 1) * 32);
                p01 = *(const f32x4*)(xr0 + (t + 1) * 32 + 4);
                p10 = *(const f32x4*)(xr1 + (t + 1) * 32);
                p11 = *(const f32x4*)(xr1 + (t + 1) * 32 + 4);
            }
            const short* wb = WTh + (size_t)t * 2048 + lane * 8;
            const short* wl = WTl + (size_t)t * 2048 + lane * 8;
            bf16x8 bh[4], bl[4];
            #pragma unroll
            for (int nt = 0; nt < 4; ++nt) {
                bh[nt] = *(const bf16x8*)(wb + nt * 512);
                bl[nt] = *(const bf16x8*)(wl + nt * 512);
            }
            bf16x8 ah0, al0, ah1, al1;
            split8(a00, a01, ah0, al0);
            split8(a10, a11, ah1, al1);
            #pragma unroll
            for (int nt = 0; nt < 4; ++nt) {
                acc[0][nt] = MFMA16(ah0, bh[nt], acc[0][nt], 0, 0, 0);
                acc[0][nt] = MFMA16(al0, bh[nt], acc[0][nt], 0, 0, 0);
                acc[0][nt] = MFMA16(ah0, bl[nt], acc[0][nt], 0, 0, 0);
                acc[1][nt] = MFMA16(ah1, bh[nt], acc[1][nt], 0, 0, 0);
                acc[1][nt] = MFMA16(al1, bh[nt], acc[1][nt], 0, 0, 0);
                acc[1][nt] = MFMA16(ah1, bl[nt], acc[1][nt], 0, 0, 0);
            }
        }
        if (wid == 3) {
            f32x4 a00 = {0,0,0,0}, a01 = {0,0,0,0}, a10 = {0,0,0,0}, a11 = {0,0,0,0};
            if (g4 == 0) {
                a00 = *(const f32x4*)(xr0 + 53 * 32);
                a10 = *(const f32x4*)(xr1 + 53 * 32);
            }
            const short* wb = WTh + (size_t)53 * 2048 + lane * 8;
            const short* wl = WTl + (size_t)53 * 2048 + lane * 8;
            bf16x8 bh[4], bl[4];
            #pragma unroll
            for (int nt = 0; nt < 4; ++nt) {
                bh[nt] = *(const bf16x8*)(wb + nt * 512);
                bl[nt] = *(const bf16x8*)(wl + nt * 512);
            }
            bf16x8 ah0, al0, ah1, al1;
            split8(a00, a01, ah0, al0);
            split8(a10, a11, ah1, al1);
            #pragma unroll
            for (int nt = 0; nt < 4; ++nt) {
                acc[0][nt] = MFMA16(ah0, bh[nt], acc[0][nt], 0, 0, 0);
                acc[0][nt] = MFMA16(al0, bh[nt], acc[0][nt], 0, 0, 0);
                acc[0][nt] = MFMA16(ah0, bl[nt], acc[0][nt], 0, 0, 0);
                acc[1][nt] = MFMA16(ah1, bh[nt], acc[1][nt], 0, 0, 0);
                acc[1][nt] = MFMA16(al1, bh[nt], acc[1][nt], 0, 0, 0);
                acc[1][nt] = MFMA16(ah1, bl[nt], acc[1][nt], 0, 0, 0);
            }
        }

        #pragma unroll
        for (int mt = 0; mt < 2; ++mt)
            #pragma unroll
            for (int nt = 0; nt < 4; ++nt)
                #pragma unroll
                for (int j = 0; j < 4; ++j)
                    red[wid][mt * 16 + g4 * 4 + j][nt * 16 + l15] = acc[mt][nt][j];
    }
    __syncthreads();

    {
        const int rr  = tid >> 3;
        const int seg = tid & 7;
        f32x4 s0 = *(const f32x4*)(b1 + seg * 8);
        f32x4 s1 = *(const f32x4*)(b1 + seg * 8 + 4);
        #pragma unroll
        for (int p = 0; p < 4; ++p) {
            s0 += *(const f32x4*)&red[p][rr][seg * 8];
            s1 += *(const f32x4*)&red[p][rr][seg * 8 + 4];
        }
        *(f32x4*)&red[0][rr][seg * 8]     = s0;
        *(f32x4*)&red[0][rr][seg * 8 + 4] = s1;
    }
    __syncthreads();
    if (wid >= 2) return;

    const int lrow = wid * 16 + l15;
    float c1[2][8], c1m1[2][8];
    #pragma unroll
    for (int kt = 0; kt < 2; ++kt) {
        f32x4 u0 = *(const f32x4*)&red[0][lrow][kt * 32 + kg];
        f32x4 u1 = *(const f32x4*)&red[0][lrow][kt * 32 + kg + 4];
        #pragma unroll
        for (int i = 0; i < 4; ++i) {
            c1[kt][i] = u0[i];     c1[kt][4 + i] = u1[i];
            c1m1[kt][i] = u0[i] - THRESH; c1m1[kt][4 + i] = u1[i] - THRESH;
        }
    }

    bf16x8 W2hf[2][2], W2lf[2][2];
    #pragma unroll
    for (int rt = 0; rt < 2; ++rt)
        #pragma unroll
        for (int kt = 0; kt < 2; ++kt) {
            const float* wp = W2 + (rt * 16 + l15) * 64 + kt * 32 + kg;
            split8(*(const f32x4*)wp, *(const f32x4*)(wp + 4), W2hf[rt][kt], W2lf[rt][kt]);
        }

    float b2v[2][4], b2m1[2][4], w3a[2][4], w3b[2][4];
    #pragma unroll
    for (int nt = 0; nt < 2; ++nt)
        #pragma unroll
        for (int j = 0; j < 4; ++j) {
            const int o = nt * 16 + g4 * 4 + j;
            b2v[nt][j]  = b2[o];
            b2m1[nt][j] = b2[o] - THRESH;
            w3a[nt][j] = W3[o];
            w3b[nt][j] = W3[32 + o];
        }

    float m1[2][8] = {};
    float m2[2][4] = {};
    const int ns = nsp[0];
    for (int s = 0; s < ns; ++s) {
        bf16x8 mh[2], ml[2];
        #pragma unroll
        for (int kt = 0; kt < 2; ++kt)
            #pragma unroll
            for (int i = 0; i < 8; ++i) {
                float m = m1[kt][i];
                m = __builtin_fmaf(BETA, m, (m > THRESH) ? c1m1[kt][i] : c1[kt][i]);
                m1[kt][i] = m;
                short h, l; split_bf(m, h, l);
                mh[kt][i] = h; ml[kt][i] = l;
            }
        f32x4 a2[2][2] = {};
        #pragma unroll
        for (int rt = 0; rt < 2; ++rt)
            #pragma unroll
            for (int kt = 0; kt < 2; ++kt) {
                a2[rt][kt] = MFMA16(W2hf[rt][kt], mh[kt], a2[rt][kt], 0, 0, 0);
                a2[rt][kt] = MFMA16(W2lf[rt][kt], mh[kt], a2[rt][kt], 0, 0, 0);
                a2[rt][kt] = MFMA16(W2hf[rt][kt], ml[kt], a2[rt][kt], 0, 0, 0);
            }
        #pragma unroll
        for (int nt = 0; nt < 2; ++nt) {
            f32x4 c2 = a2[nt][0] + a2[nt][1];
            #pragma unroll
            for (int j = 0; j < 4; ++j) {
                float m = m2[nt][j];
                m2[nt][j] = __builtin_fmaf(
                    BETA, m, c2[j] + ((m > THRESH) ? b2m1[nt][j] : b2v[nt][j]));
            }
        }
    }

    float p0 = 0.f, p1 = 0.f;
    #pragma unroll
    for (int nt = 0; nt < 2; ++nt)
        #pragma unroll
        for (int j = 0; j < 4; ++j) {
            p0 = __builtin_fmaf(m2[nt][j], w3a[nt][j], p0);
            p1 = __builtin_fmaf(m2[nt][j], w3b[nt][j], p1);
        }
    p0 += __shfl_xor(p0, 16); p0 += __shfl_xor(p0, 32);
    p1 += __shfl_xor(p1, 16); p1 += __shfl_xor(p1, 32);
    if (lane < 16) {
        const size_t row = rowBase + lrow;
        out[row * 2 + 0] = p0 + b3[0];
        out[row * 2 + 1] = p1 + b3[1];
    }
}

extern "C" void kernel_launch(void* const* d_in, const int* in_sizes, int n_in,
                              void* d_out, int out_size, void* d_ws, size_t ws_size,
                              hipStream_t stream) {
    const float* x  = (const float*)d_in[0];
    const float* W1 = (const float*)d_in[1];
    const float* b1 = (const float*)d_in[2];
    const float* W2 = (const float*)d_in[3];
    const float* b2 = (const float*)d_in[4];
    const float* W3 = (const float*)d_in[5];
    const float* b3 = (const float*)d_in[6];
    const int*   ns = (const int*)d_in[7];
    float* o = (float*)d_out;

    const int B = in_sizes[0] / KDIM;              // 16384
    short* WTh  = (short*)d_ws;                    // [54][2048] bf16 hi
    short* WTl  = WTh + (size_t)NKT * 2048;        // [54][2048] bf16 lo
    float* pscr = (float*)((char*)d_ws + (1 << 20));   // probe scratch, 4 MB

    w1_relayout<<<NKT, 256, 0, stream>>>(W1, WTh, WTl);
    probe_noW <<<B / 32, 256, 0, stream>>>(x, WTh, WTl, b1, pscr, 8);
    probe_noX <<<B / 32, 256, 0, stream>>>(x, WTh, WTl, b1, pscr, 8);
    probe_base<<<B / 32, 256, 0, stream>>>(x, WTh, WTl, b1, pscr, 3);
    snn_fused <<<B / 32, 256, 0, stream>>>(x, WTh, WTl, b1, W2, b2, W3, b3, ns, o);
}

// Round 10
// 46.885 us; speedup vs baseline: 6.8693x; 6.8693x over previous
//
#include <hip/hip_runtime.h>
#include <hip/hip_bf16.h>

typedef float f32x4 __attribute__((ext_vector_type(4)));
typedef short bf16x8 __attribute__((ext_vector_type(8)));

#define MFMA16 __builtin_amdgcn_mfma_f32_16x16x32_bf16

static constexpr int KDIM = 1700;
static constexpr int NKT2 = 56;         // padded k-tiles: 54 real (53 ragged) + 2 zero
static constexpr float BETA = 0.9f;
static constexpr float THRESH = 1.0f;

// fp32 -> bf16 hi + bf16 lo (residual), via HW cvt
__device__ __forceinline__ void split_bf(float f, short& hi, short& lo) {
    __hip_bfloat16 h = __float2bfloat16(f);
    float r = f - __bfloat162float(h);          // exact in fp32
    __hip_bfloat16 l = __float2bfloat16(r);
    hi = (short)__builtin_bit_cast(unsigned short, h);
    lo = (short)__builtin_bit_cast(unsigned short, l);
}

__device__ __forceinline__ void split8(f32x4 a, f32x4 b, bf16x8& hi, bf16x8& lo) {
    #pragma unroll
    for (int i = 0; i < 4; ++i) { short h, l; split_bf(a[i], h, l); hi[i] = h; lo[i] = l; }
    #pragma unroll
    for (int i = 0; i < 4; ++i) { short h, l; split_bf(b[i], h, l); hi[4 + i] = h; lo[4 + i] = l; }
}

// W1 [64][1700] f32 -> two bf16 planes in MFMA-B-fragment order, 56 k-tiles
// (k >= 1700 zero-padded):
// WT[((kt*4 + nt)*64 + lane)*8 + i] = W1[nt*16 + (lane&15)][kt*32 + (lane>>4)*8 + i]
__global__ void w1_relayout(const float* __restrict__ W1,
                            short* __restrict__ WTh, short* __restrict__ WTl) {
    const int g    = blockIdx.x * 256 + threadIdx.x;   // 0 .. 56*256-1
    const int kt   = g >> 8;
    const int nt   = (g >> 6) & 3;
    const int lane = g & 63;
    const int n    = nt * 16 + (lane & 15);
    const int kb   = kt * 32 + (lane >> 4) * 8;
    bf16x8 vh, vl;
    #pragma unroll
    for (int i = 0; i < 8; ++i) {
        const int k = kb + i;
        const float v = (k < KDIM) ? W1[n * KDIM + k] : 0.f;
        short h, l; split_bf(v, h, l);
        vh[i] = h; vl[i] = l;
    }
    *(bf16x8*)(WTh + (size_t)g * 8) = vh;
    *(bf16x8*)(WTl + (size_t)g * 8) = vl;
}

// ---------------- fused kernel: cur1 GEMM (in LDS) + LIF recurrence ----------
// 256 thr = 4 waves, 32 rows/block, K-split-4: wave w owns k-tiles
// [14w, 14w+14). Fully static 14-step software pipeline per wave:
//   step i: issue W(i+1) -> WN ; split8(x(i)) ; issue x(i+3) -> same ring slot ;
//           16 MFMA with WC.
// W issued BEFORE x each step, x ring 3 deep => a vmcnt wait for W(i) only
// drains x-loads that are >=2 steps old (complete), so the HBM x stream stays
// off the critical path (vmcnt completes in order; see r9 ablation).
__global__ __launch_bounds__(256, 2) void snn_fused(
    const float* __restrict__ x,
    const short* __restrict__ WTh, const short* __restrict__ WTl,
    const float* __restrict__ b1, const float* __restrict__ W2,
    const float* __restrict__ b2, const float* __restrict__ W3,
    const float* __restrict__ b3, const int* __restrict__ nsp,
    float* __restrict__ out)
{
    __shared__ float red[4][32][68];
    const int tid = threadIdx.x;
    const int wid = tid >> 6;
    const int lane = tid & 63;
    const int l15 = lane & 15;
    const int g4  = lane >> 4;
    const int kg  = g4 * 8;
    const int rowBase = blockIdx.x * 32;
    const int t0  = wid * 14;                 // 14 tiles per wave, uniform

    const float* xr0 = x + (size_t)(rowBase + l15) * KDIM;
    const float* xr1 = xr0 + (size_t)16 * KDIM;
    const short* pWh = WTh + (size_t)t0 * 2048 + lane * 8;
    const short* pWl = WTl + (size_t)t0 * 2048 + lane * 8;

    struct XB { f32x4 a0, a1, b0, b1; };
    // x fragment load; addresses clamped in-row for k >= 1700 (the matching W
    // entries are zero, so garbage-but-finite x values contribute 0).
    auto xload = [&](int t, XB& xb) {
        const int k1 = t * 32 + kg;
        const int k2 = k1 + 4;
        const int kc1 = (k1 <= 1696) ? k1 : 1664;
        const int kc2 = (k2 <= 1696) ? k2 : 1664;
        xb.a0 = *(const f32x4*)(xr0 + kc1);
        xb.a1 = *(const f32x4*)(xr0 + kc2);
        xb.b0 = *(const f32x4*)(xr1 + kc1);
        xb.b1 = *(const f32x4*)(xr1 + kc2);
    };
    auto wload = [&](int i, bf16x8* Wf) {     // i static 0..13
        #pragma unroll
        for (int nt = 0; nt < 4; ++nt) {
            Wf[nt]     = *(const bf16x8*)(pWh + (size_t)i * 2048 + nt * 512);
            Wf[4 + nt] = *(const bf16x8*)(pWl + (size_t)i * 2048 + nt * 512);
        }
    };

    f32x4 acc[2][4] = {};
    XB x0, x1, x2;
    bf16x8 WA[8], WB[8];

    wload(0, WA);                             // W first: oldest in queue
    xload(t0 + 0, x0);
    xload(t0 + 1, x1);
    xload(t0 + 2, x2);

#define GSTEP(I, XC, WC, WN)                                               \
    {                                                                      \
        if constexpr ((I) + 1 < 14) wload((I) + 1, WN);                    \
        bf16x8 ah0, al0, ah1, al1;                                         \
        split8(XC.a0, XC.a1, ah0, al0);                                    \
        split8(XC.b0, XC.b1, ah1, al1);                                    \
        if constexpr ((I) + 3 < 14) xload(t0 + (I) + 3, XC);               \
        _Pragma("unroll")                                                  \
        for (int nt = 0; nt < 4; ++nt) {                                   \
            acc[0][nt] = MFMA16(ah0, WC[nt],     acc[0][nt], 0, 0, 0);     \
            acc[0][nt] = MFMA16(al0, WC[nt],     acc[0][nt], 0, 0, 0);     \
            acc[0][nt] = MFMA16(ah0, WC[4 + nt], acc[0][nt], 0, 0, 0);     \
            acc[1][nt] = MFMA16(ah1, WC[nt],     acc[1][nt], 0, 0, 0);     \
            acc[1][nt] = MFMA16(al1, WC[nt],     acc[1][nt], 0, 0, 0);     \
            acc[1][nt] = MFMA16(ah1, WC[4 + nt], acc[1][nt], 0, 0, 0);     \
        }                                                                  \
    }

    GSTEP(0,  x0, WA, WB)
    GSTEP(1,  x1, WB, WA)
    GSTEP(2,  x2, WA, WB)
    GSTEP(3,  x0, WB, WA)
    GSTEP(4,  x1, WA, WB)
    GSTEP(5,  x2, WB, WA)
    GSTEP(6,  x0, WA, WB)
    GSTEP(7,  x1, WB, WA)
    GSTEP(8,  x2, WA, WB)
    GSTEP(9,  x0, WB, WA)
    GSTEP(10, x1, WA, WB)
    GSTEP(11, x2, WB, WA)
    GSTEP(12, x0, WA, WB)
    GSTEP(13, x1, WB, WA)
#undef GSTEP

    // partials -> LDS (C-layout: row = mt*16 + g4*4 + j, col = nt*16 + l15)
    #pragma unroll
    for (int mt = 0; mt < 2; ++mt)
        #pragma unroll
        for (int nt = 0; nt < 4; ++nt)
            #pragma unroll
            for (int j = 0; j < 4; ++j)
                red[wid][mt * 16 + g4 * 4 + j][nt * 16 + l15] = acc[mt][nt][j];
    __syncthreads();

    // reduce 4 k-partials + b1 into red[0] (disjoint (rr,seg) slots: race-free)
    {
        const int rr  = tid >> 3;
        const int seg = tid & 7;
        f32x4 s0 = *(const f32x4*)(b1 + seg * 8);
        f32x4 s1 = *(const f32x4*)(b1 + seg * 8 + 4);
        #pragma unroll
        for (int p = 0; p < 4; ++p) {
            s0 += *(const f32x4*)&red[p][rr][seg * 8];
            s1 += *(const f32x4*)&red[p][rr][seg * 8 + 4];
        }
        *(f32x4*)&red[0][rr][seg * 8]     = s0;
        *(f32x4*)&red[0][rr][seg * 8 + 4] = s1;
    }
    __syncthreads();
    if (wid >= 2) return;                     // waves 2,3 done (no barriers below)

    // ---------------- phase 2: 20-step LIF recurrence, all in registers ------
    const int lrow = wid * 16 + l15;

    float c1[2][8], c1m1[2][8];
    #pragma unroll
    for (int kt = 0; kt < 2; ++kt) {
        f32x4 u0 = *(const f32x4*)&red[0][lrow][kt * 32 + kg];
        f32x4 u1 = *(const f32x4*)&red[0][lrow][kt * 32 + kg + 4];
        #pragma unroll
        for (int i = 0; i < 4; ++i) {
            c1[kt][i] = u0[i];     c1[kt][4 + i] = u1[i];
            c1m1[kt][i] = u0[i] - THRESH; c1m1[kt][4 + i] = u1[i] - THRESH;
        }
    }

    bf16x8 W2hf[2][2], W2lf[2][2];
    #pragma unroll
    for (int rt = 0; rt < 2; ++rt)
        #pragma unroll
        for (int kt = 0; kt < 2; ++kt) {
            const float* wp = W2 + (rt * 16 + l15) * 64 + kt * 32 + kg;
            split8(*(const f32x4*)wp, *(const f32x4*)(wp + 4), W2hf[rt][kt], W2lf[rt][kt]);
        }

    float b2v[2][4], b2m1[2][4], w3a[2][4], w3b[2][4];
    #pragma unroll
    for (int nt = 0; nt < 2; ++nt)
        #pragma unroll
        for (int j = 0; j < 4; ++j) {
            const int o = nt * 16 + g4 * 4 + j;
            b2v[nt][j]  = b2[o];
            b2m1[nt][j] = b2[o] - THRESH;
            w3a[nt][j] = W3[o];
            w3b[nt][j] = W3[32 + o];
        }

    float m1[2][8] = {};
    float m2[2][4] = {};
    const int ns = nsp[0];
    for (int s = 0; s < ns; ++s) {
        bf16x8 mh[2], ml[2];
        #pragma unroll
        for (int kt = 0; kt < 2; ++kt)
            #pragma unroll
            for (int i = 0; i < 8; ++i) {
                float m = m1[kt][i];
                m = __builtin_fmaf(BETA, m, (m > THRESH) ? c1m1[kt][i] : c1[kt][i]);
                m1[kt][i] = m;
                short h, l; split_bf(m, h, l);
                mh[kt][i] = h; ml[kt][i] = l;
            }
        f32x4 a2[2][2] = {};
        #pragma unroll
        for (int rt = 0; rt < 2; ++rt)
            #pragma unroll
            for (int kt = 0; kt < 2; ++kt) {
                a2[rt][kt] = MFMA16(W2hf[rt][kt], mh[kt], a2[rt][kt], 0, 0, 0);
                a2[rt][kt] = MFMA16(W2lf[rt][kt], mh[kt], a2[rt][kt], 0, 0, 0);
                a2[rt][kt] = MFMA16(W2hf[rt][kt], ml[kt], a2[rt][kt], 0, 0, 0);
            }
        #pragma unroll
        for (int nt = 0; nt < 2; ++nt) {
            f32x4 c2 = a2[nt][0] + a2[nt][1];
            #pragma unroll
            for (int j = 0; j < 4; ++j) {
                float m = m2[nt][j];
                m2[nt][j] = __builtin_fmaf(
                    BETA, m, c2[j] + ((m > THRESH) ? b2m1[nt][j] : b2v[nt][j]));
            }
        }
    }

    float p0 = 0.f, p1 = 0.f;
    #pragma unroll
    for (int nt = 0; nt < 2; ++nt)
        #pragma unroll
        for (int j = 0; j < 4; ++j) {
            p0 = __builtin_fmaf(m2[nt][j], w3a[nt][j], p0);
            p1 = __builtin_fmaf(m2[nt][j], w3b[nt][j], p1);
        }
    p0 += __shfl_xor(p0, 16); p0 += __shfl_xor(p0, 32);
    p1 += __shfl_xor(p1, 16); p1 += __shfl_xor(p1, 32);
    if (lane < 16) {
        const size_t row = rowBase + lrow;
        out[row * 2 + 0] = p0 + b3[0];
        out[row * 2 + 1] = p1 + b3[1];
    }
}

extern "C" void kernel_launch(void* const* d_in, const int* in_sizes, int n_in,
                              void* d_out, int out_size, void* d_ws, size_t ws_size,
                              hipStream_t stream) {
    const float* x  = (const float*)d_in[0];
    const float* W1 = (const float*)d_in[1];
    const float* b1 = (const float*)d_in[2];
    const float* W2 = (const float*)d_in[3];
    const float* b2 = (const float*)d_in[4];
    const float* W3 = (const float*)d_in[5];
    const float* b3 = (const float*)d_in[6];
    const int*   ns = (const int*)d_in[7];
    float* o = (float*)d_out;

    const int B = in_sizes[0] / KDIM;              // 16384
    short* WTh  = (short*)d_ws;                    // [56][2048] bf16 hi
    short* WTl  = WTh + (size_t)NKT2 * 2048;       // [56][2048] bf16 lo

    w1_relayout<<<NKT2, 256, 0, stream>>>(W1, WTh, WTl);
    snn_fused<<<B / 32, 256, 0, stream>>>(x, WTh, WTl, b1, W2, b2, W3, b3, ns, o);
}

// Round 11
// 43.929 us; speedup vs baseline: 7.3316x; 1.0673x over previous
//
#include <hip/hip_runtime.h>
#include <hip/hip_bf16.h>

typedef float f32x4 __attribute__((ext_vector_type(4)));
typedef short bf16x8 __attribute__((ext_vector_type(8)));

#define MFMA16 __builtin_amdgcn_mfma_f32_16x16x32_bf16

static constexpr int KDIM = 1700;
static constexpr int NKT2 = 56;         // padded k-tiles: 54 real (53 ragged) + 2 zero
static constexpr float BETA = 0.9f;
static constexpr float THRESH = 1.0f;

// fp32 -> bf16 hi + bf16 lo (residual), via HW cvt
__device__ __forceinline__ void split_bf(float f, short& hi, short& lo) {
    __hip_bfloat16 h = __float2bfloat16(f);
    float r = f - __bfloat162float(h);          // exact in fp32
    __hip_bfloat16 l = __float2bfloat16(r);
    hi = (short)__builtin_bit_cast(unsigned short, h);
    lo = (short)__builtin_bit_cast(unsigned short, l);
}

__device__ __forceinline__ void split8(f32x4 a, f32x4 b, bf16x8& hi, bf16x8& lo) {
    #pragma unroll
    for (int i = 0; i < 4; ++i) { short h, l; split_bf(a[i], h, l); hi[i] = h; lo[i] = l; }
    #pragma unroll
    for (int i = 0; i < 4; ++i) { short h, l; split_bf(b[i], h, l); hi[4 + i] = h; lo[4 + i] = l; }
}

// W1 [64][1700] f32 -> two bf16 planes in MFMA-B-fragment order, 56 k-tiles
// (k >= 1700 zero-padded):
// WT[((kt*4 + nt)*64 + lane)*8 + i] = W1[nt*16 + (lane&15)][kt*32 + (lane>>4)*8 + i]
__global__ void w1_relayout(const float* __restrict__ W1,
                            short* __restrict__ WTh, short* __restrict__ WTl) {
    const int g    = blockIdx.x * 256 + threadIdx.x;   // 0 .. 56*256-1
    const int kt   = g >> 8;
    const int nt   = (g >> 6) & 3;
    const int lane = g & 63;
    const int n    = nt * 16 + (lane & 15);
    const int kb   = kt * 32 + (lane >> 4) * 8;
    bf16x8 vh, vl;
    #pragma unroll
    for (int i = 0; i < 8; ++i) {
        const int k = kb + i;
        const float v = (k < KDIM) ? W1[n * KDIM + k] : 0.f;
        short h, l; split_bf(v, h, l);
        vh[i] = h; vl[i] = l;
    }
    *(bf16x8*)(WTh + (size_t)g * 8) = vh;
    *(bf16x8*)(WTl + (size_t)g * 8) = vl;
}

__device__ __forceinline__ void gll16(const short* src, const short* lds_dst) {
    __builtin_amdgcn_global_load_lds(
        (const __attribute__((address_space(1))) unsigned int*)src,
        (__attribute__((address_space(3))) unsigned int*)lds_dst, 16, 0, 0);
}

// ---------------- fused kernel: cur1 GEMM (LDS-staged W) + LIF recurrence ----
// 256 thr = 4 waves, 32 rows/block, K-split-4: wave w owns 14 k-tiles.
// W streams HBM/L2 -> wave-private LDS dbuf (global_load_lds, vmcnt);
// x streams via inline-asm global_load_dwordx4, 3-step register ring.
// One counted s_waitcnt vmcnt(N) per step (issue order makes the count exact);
// x loads keep ~3 steps of latency slack and are never drained early.
__global__ __launch_bounds__(256, 2) void snn_fused(
    const float* __restrict__ x,
    const short* __restrict__ WTh, const short* __restrict__ WTl,
    const float* __restrict__ b1, const float* __restrict__ W2,
    const float* __restrict__ b2, const float* __restrict__ W3,
    const float* __restrict__ b3, const int* __restrict__ nsp,
    float* __restrict__ out)
{
    __shared__ __align__(16) char smemraw[65536];   // ldsW (64KB) / red (aliased)
    short* ldsW = (short*)smemraw;
    float (*red)[32][68] = (float (*)[32][68])smemraw;

    const int tid = threadIdx.x;
    const int wid = tid >> 6;
    const int lane = tid & 63;
    const int l15 = lane & 15;
    const int g4  = lane >> 4;
    const int kg  = g4 * 8;
    const int rowBase = blockIdx.x * 32;
    const int t0  = wid * 14;

    const float* xr0 = x + (size_t)(rowBase + l15) * KDIM;
    const float* xr1 = xr0 + (size_t)16 * KDIM;
    const short* pWh = WTh + (size_t)t0 * 2048 + lane * 8;  // per-lane W src
    const short* pWl = WTl + (size_t)t0 * 2048 + lane * 8;
    short* myLds = ldsW + wid * 8192;              // 16KB/wave (2 x 8KB bufs)

    struct XB { f32x4 a0, a1, b0, b1; };
    // x fragment load via inline asm (pinned issue point; NO auto-waitcnt —
    // consumption is guarded by the explicit counted vmcnt below).
    // Addresses clamped in-row for k >= 1700 (matching W entries are zero).
    auto xload = [&](int t, XB& xb) {
        const int k1 = t * 32 + kg;
        const int kc1 = (k1 <= 1696) ? k1 : 1664;
        const int kc2 = (k1 + 4 <= 1696) ? k1 + 4 : 1664;
        const float* p0 = xr0 + kc1;
        const float* p1 = xr0 + kc2;
        const float* p2 = xr1 + kc1;
        const float* p3 = xr1 + kc2;
        asm volatile("global_load_dwordx4 %0, %1, off" : "=v"(xb.a0) : "v"(p0));
        asm volatile("global_load_dwordx4 %0, %1, off" : "=v"(xb.a1) : "v"(p1));
        asm volatile("global_load_dwordx4 %0, %1, off" : "=v"(xb.b0) : "v"(p2));
        asm volatile("global_load_dwordx4 %0, %1, off" : "=v"(xb.b1) : "v"(p3));
    };
    // stage tile (t0+i) into my wave's LDS buffer `buf` (8 x 1KB, vmcnt-tracked)
    auto stageW = [&](int i, int buf) {
        short* dstb = myLds + buf * 4096;
        #pragma unroll
        for (int q = 0; q < 4; ++q) {
            gll16(pWh + (size_t)i * 2048 + q * 512, dstb + q * 512);
            gll16(pWl + (size_t)i * 2048 + q * 512, dstb + 2048 + q * 512);
        }
    };

    f32x4 acc[2][4] = {};
    XB x0, x1, x2;

    // prologue issue order: W0, x0, x1, W1, x2  (28 outstanding)
    stageW(0, 0);
    xload(t0 + 0, x0);
    xload(t0 + 1, x1);
    stageW(1, 1);
    xload(t0 + 2, x2);

    // step I: wait vmcnt(WAITN) completes W(I)+x(I), keeps newer loads flying.
#define GSTEP(I, XC, WAITN)                                                    \
    {                                                                          \
        asm volatile("s_waitcnt vmcnt(" #WAITN ")" ::: "memory");              \
        __builtin_amdgcn_sched_barrier(0);                                     \
        const short* rb = myLds + ((I) & 1) * 4096;                            \
        bf16x8 WC[8];                                                          \
        _Pragma("unroll")                                                      \
        for (int q = 0; q < 8; ++q)                                            \
            WC[q] = *(const bf16x8*)(rb + q * 512 + lane * 8);                 \
        bf16x8 ah0, al0, ah1, al1;                                             \
        split8(XC.a0, XC.a1, ah0, al0);                                        \
        split8(XC.b0, XC.b1, ah1, al1);                                        \
        asm volatile("s_waitcnt lgkmcnt(0)" ::: "memory");                     \
        __builtin_amdgcn_sched_barrier(0);                                     \
        if constexpr ((I) + 2 < 14) stageW((I) + 2, (I) & 1);                  \
        if constexpr ((I) + 3 < 14) xload(t0 + (I) + 3, XC);                   \
        __builtin_amdgcn_sched_barrier(0);                                     \
        _Pragma("unroll")                                                      \
        for (int nt = 0; nt < 4; ++nt) {                                       \
            acc[0][nt] = MFMA16(ah0, WC[nt],     acc[0][nt], 0, 0, 0);         \
            acc[0][nt] = MFMA16(al0, WC[nt],     acc[0][nt], 0, 0, 0);         \
            acc[0][nt] = MFMA16(ah0, WC[4 + nt], acc[0][nt], 0, 0, 0);         \
            acc[1][nt] = MFMA16(ah1, WC[nt],     acc[1][nt], 0, 0, 0);         \
            acc[1][nt] = MFMA16(al1, WC[nt],     acc[1][nt], 0, 0, 0);         \
            acc[1][nt] = MFMA16(ah1, WC[4 + nt], acc[1][nt], 0, 0, 0);         \
        }                                                                      \
    }

    GSTEP(0,  x0, 16)
    GSTEP(1,  x1, 16)
    GSTEP(2,  x2, 16)
    GSTEP(3,  x0, 16)
    GSTEP(4,  x1, 16)
    GSTEP(5,  x2, 16)
    GSTEP(6,  x0, 16)
    GSTEP(7,  x1, 16)
    GSTEP(8,  x2, 16)
    GSTEP(9,  x0, 16)
    GSTEP(10, x1, 16)
    GSTEP(11, x2, 16)
    GSTEP(12, x0, 12)
    GSTEP(13, x1, 0)
#undef GSTEP

    // ldsW regions of different waves alias red[] -> sync BEFORE overwriting
    __syncthreads();

    // partials -> LDS (C-layout: row = mt*16 + g4*4 + j, col = nt*16 + l15)
    #pragma unroll
    for (int mt = 0; mt < 2; ++mt)
        #pragma unroll
        for (int nt = 0; nt < 4; ++nt)
            #pragma unroll
            for (int j = 0; j < 4; ++j)
                red[wid][mt * 16 + g4 * 4 + j][nt * 16 + l15] = acc[mt][nt][j];
    __syncthreads();

    // reduce 4 k-partials + b1 into red[0] (disjoint (rr,seg) slots: race-free)
    {
        const int rr  = tid >> 3;
        const int seg = tid & 7;
        f32x4 s0 = *(const f32x4*)(b1 + seg * 8);
        f32x4 s1 = *(const f32x4*)(b1 + seg * 8 + 4);
        #pragma unroll
        for (int p = 0; p < 4; ++p) {
            s0 += *(const f32x4*)&red[p][rr][seg * 8];
            s1 += *(const f32x4*)&red[p][rr][seg * 8 + 4];
        }
        *(f32x4*)&red[0][rr][seg * 8]     = s0;
        *(f32x4*)&red[0][rr][seg * 8 + 4] = s1;
    }
    __syncthreads();
    if (wid >= 2) return;                     // waves 2,3 done (no barriers below)

    // ---------------- phase 2: 20-step LIF recurrence, all in registers ------
    const int lrow = wid * 16 + l15;

    float c1[2][8], c1m1[2][8];
    #pragma unroll
    for (int kt = 0; kt < 2; ++kt) {
        f32x4 u0 = *(const f32x4*)&red[0][lrow][kt * 32 + kg];
        f32x4 u1 = *(const f32x4*)&red[0][lrow][kt * 32 + kg + 4];
        #pragma unroll
        for (int i = 0; i < 4; ++i) {
            c1[kt][i] = u0[i];     c1[kt][4 + i] = u1[i];
            c1m1[kt][i] = u0[i] - THRESH; c1m1[kt][4 + i] = u1[i] - THRESH;
        }
    }

    bf16x8 W2hf[2][2], W2lf[2][2];
    #pragma unroll
    for (int rt = 0; rt < 2; ++rt)
        #pragma unroll
        for (int kt = 0; kt < 2; ++kt) {
            const float* wp = W2 + (rt * 16 + l15) * 64 + kt * 32 + kg;
            split8(*(const f32x4*)wp, *(const f32x4*)(wp + 4), W2hf[rt][kt], W2lf[rt][kt]);
        }

    float b2v[2][4], b2m1[2][4], w3a[2][4], w3b[2][4];
    #pragma unroll
    for (int nt = 0; nt < 2; ++nt)
        #pragma unroll
        for (int j = 0; j < 4; ++j) {
            const int o = nt * 16 + g4 * 4 + j;
            b2v[nt][j]  = b2[o];
            b2m1[nt][j] = b2[o] - THRESH;
            w3a[nt][j] = W3[o];
            w3b[nt][j] = W3[32 + o];
        }

    float m1[2][8] = {};
    float m2[2][4] = {};
    const int ns = nsp[0];
    for (int s = 0; s < ns; ++s) {
        bf16x8 mh[2], ml[2];
        #pragma unroll
        for (int kt = 0; kt < 2; ++kt)
            #pragma unroll
            for (int i = 0; i < 8; ++i) {
                float m = m1[kt][i];
                m = __builtin_fmaf(BETA, m, (m > THRESH) ? c1m1[kt][i] : c1[kt][i]);
                m1[kt][i] = m;
                short h, l; split_bf(m, h, l);
                mh[kt][i] = h; ml[kt][i] = l;
            }
        f32x4 a2[2][2] = {};
        #pragma unroll
        for (int rt = 0; rt < 2; ++rt)
            #pragma unroll
            for (int kt = 0; kt < 2; ++kt) {
                a2[rt][kt] = MFMA16(W2hf[rt][kt], mh[kt], a2[rt][kt], 0, 0, 0);
                a2[rt][kt] = MFMA16(W2lf[rt][kt], mh[kt], a2[rt][kt], 0, 0, 0);
                a2[rt][kt] = MFMA16(W2hf[rt][kt], ml[kt], a2[rt][kt], 0, 0, 0);
            }
        #pragma unroll
        for (int nt = 0; nt < 2; ++nt) {
            f32x4 c2 = a2[nt][0] + a2[nt][1];
            #pragma unroll
            for (int j = 0; j < 4; ++j) {
                float m = m2[nt][j];
                m2[nt][j] = __builtin_fmaf(
                    BETA, m, c2[j] + ((m > THRESH) ? b2m1[nt][j] : b2v[nt][j]));
            }
        }
    }

    float p0 = 0.f, p1 = 0.f;
    #pragma unroll
    for (int nt = 0; nt < 2; ++nt)
        #pragma unroll
        for (int j = 0; j < 4; ++j) {
            p0 = __builtin_fmaf(m2[nt][j], w3a[nt][j], p0);
            p1 = __builtin_fmaf(m2[nt][j], w3b[nt][j], p1);
        }
    p0 += __shfl_xor(p0, 16); p0 += __shfl_xor(p0, 32);
    p1 += __shfl_xor(p1, 16); p1 += __shfl_xor(p1, 32);
    if (lane < 16) {
        const size_t row = rowBase + lrow;
        out[row * 2 + 0] = p0 + b3[0];
        out[row * 2 + 1] = p1 + b3[1];
    }
}

extern "C" void kernel_launch(void* const* d_in, const int* in_sizes, int n_in,
                              void* d_out, int out_size, void* d_ws, size_t ws_size,
                              hipStream_t stream) {
    const float* x  = (const float*)d_in[0];
    const float* W1 = (const float*)d_in[1];
    const float* b1 = (const float*)d_in[2];
    const float* W2 = (const float*)d_in[3];
    const float* b2 = (const float*)d_in[4];
    const float* W3 = (const float*)d_in[5];
    const float* b3 = (const float*)d_in[6];
    const int*   ns = (const int*)d_in[7];
    float* o = (float*)d_out;

    const int B = in_sizes[0] / KDIM;              // 16384
    short* WTh  = (short*)d_ws;                    // [56][2048] bf16 hi
    short* WTl  = WTh + (size_t)NKT2 * 2048;       // [56][2048] bf16 lo

    w1_relayout<<<NKT2, 256, 0, stream>>>(W1, WTh, WTl);
    snn_fused<<<B / 32, 256, 0, stream>>>(x, WTh, WTl, b1, W2, b2, W3, b3, ns, o);
}